// Round 12
// baseline (636.430 us; speedup 1.0000x reference)
//
#include <hip/hip_runtime.h>
#include <cstdint>
#include <cstddef>

// Problem constants (match reference)
#define FEAT 128          // IN_DIM == HID
#define NLAYERS 3
#define EPS 1e-5f
#define TILE 8192         // edges per radix-partition tile
#define SBSHIFT 9         // 512 nodes per super-bucket (N<=131072 -> SB<=256)

typedef unsigned int uint32;
typedef float floatx2 __attribute__((ext_vector_type(2)));

// pack two fp32 -> bf16 pair (RNE), low = even feature, high = odd feature
__device__ __forceinline__ uint32 pack_bf16(float a, float b) {
  uint32 ua = __float_as_uint(a);
  uint32 ub = __float_as_uint(b);
  ua += 0x7fffu + ((ua >> 16) & 1u);
  ub += 0x7fffu + ((ub >> 16) & 1u);
  return (ua >> 16) | (ub & 0xffff0000u);
}

// ---------------------------------------------------------------------------
// generic: per-256-block sums
__global__ void scan1(const int* __restrict__ in, int* __restrict__ bsum, int n) {
  __shared__ int s[256];
  int t = threadIdx.x;
  int i = blockIdx.x * 256 + t;
  s[t] = (i < n) ? in[i] : 0;
  __syncthreads();
  for (int o = 128; o > 0; o >>= 1) {
    if (t < o) s[t] += s[t + o];
    __syncthreads();
  }
  if (t == 0) bsum[blockIdx.x] = s[0];
}

// generic: single-block exclusive scan of block sums (nb <= 512)
__global__ void scan2(int* __restrict__ bsum, int nb) {
  __shared__ int s[512];
  int t = threadIdx.x;
  int v = (t < nb) ? bsum[t] : 0;
  s[t] = v;
  __syncthreads();
  for (int o = 1; o < 512; o <<= 1) {
    int add = (t >= o) ? s[t - o] : 0;
    __syncthreads();
    s[t] += add;
    __syncthreads();
  }
  if (t < nb) bsum[t] = s[t] - v;  // exclusive
}

// generic final scan: exclusive values written in-place (out may == in)
__global__ void gscan3(const int* __restrict__ in, const int* __restrict__ bsum,
                       int* __restrict__ out, int n) {
  __shared__ int s[256];
  int t = threadIdx.x;
  int i = blockIdx.x * 256 + t;
  int v = (i < n) ? in[i] : 0;
  s[t] = v;
  __syncthreads();
  for (int o = 1; o < 256; o <<= 1) {
    int add = (t >= o) ? s[t - o] : 0;
    __syncthreads();
    s[t] += add;
    __syncthreads();
  }
  if (i < n) out[i] = bsum[blockIdx.x] + s[t] - v;
}

// ---------------------------------------------------------------------------
// Radix partition level 1: count per (super-bucket, tile); bucket-major C.
// ---------------------------------------------------------------------------
__global__ __launch_bounds__(256) void l1count_k(const int* __restrict__ col,
                                                 int* __restrict__ C, int E, int NT,
                                                 int SB) {
  __shared__ int h[256];
  int t = threadIdx.x;
  h[t] = 0;
  __syncthreads();
  int base = blockIdx.x * TILE;
  int end = min(base + TILE, E);
  for (int i = base + t; i < end; i += 256) atomicAdd(&h[col[i] >> SBSHIFT], 1);
  __syncthreads();
  if (t < SB) C[t * NT + blockIdx.x] = h[t];
}

// level 1 scatter: contiguous runs per (tile,bucket); LDS atomics only.
// packed: (localcol 9b) << 17 | row (17b, N < 131072)
__global__ __launch_bounds__(256) void l1scatter_k(const int* __restrict__ row,
                                                   const int* __restrict__ col,
                                                   const int* __restrict__ Cex,
                                                   uint32* __restrict__ bbuf, int E, int NT,
                                                   int SB) {
  __shared__ int cur[256];
  int t = threadIdx.x;
  if (t < SB) cur[t] = Cex[t * NT + blockIdx.x];
  __syncthreads();
  int base = blockIdx.x * TILE;
  int end = min(base + TILE, E);
  for (int i = base + t; i < end; i += 256) {
    int c = col[i];
    int pos = atomicAdd(&cur[c >> SBSHIFT], 1);
    bbuf[pos] = ((uint32)(c & ((1 << SBSHIFT) - 1)) << 17) | (uint32)row[i];
  }
}

// ---------------------------------------------------------------------------
// Level 2 (fused): one block per super-bucket.
//   pass 1: LDS histogram of the bucket's 512 nodes (LDS atomics only)
//   LDS exclusive scan -> rowstart[n] = bucketStart + localExcl, dis[n]
//   pass 2: LDS cursors -> scatter csrc into the bucket's private window
// No global atomics anywhere; csrc writes confined to a contiguous window.
// ---------------------------------------------------------------------------
__global__ __launch_bounds__(256) void l2_k(const uint32* __restrict__ bbuf,
                                            const int* __restrict__ Cex,
                                            int* __restrict__ rowstart,
                                            float* __restrict__ dis,
                                            int* __restrict__ csrc,
                                            int N, int E, int NT, int SB) {
  __shared__ int hist[512];     // counts -> cursors
  __shared__ int scanbuf[256];  // pair-sum scan
  const int b = blockIdx.x;
  const int t = threadIdx.x;
  const int n0 = b << SBSHIFT;
  hist[t] = 0;
  hist[t + 256] = 0;
  __syncthreads();
  const int s = Cex[b * NT];
  const int e1 = (b == SB - 1) ? E : Cex[(b + 1) * NT];
  for (int i = s + t; i < e1; i += 256) {
    atomicAdd(&hist[bbuf[i] >> 17], 1);
  }
  __syncthreads();
  // exclusive scan of 512 counts: thread t owns elements 2t, 2t+1
  int a0 = hist[2 * t];
  int a1 = hist[2 * t + 1];
  int pair = a0 + a1;
  scanbuf[t] = pair;
  __syncthreads();
  for (int o = 1; o < 256; o <<= 1) {
    int add = (t >= o) ? scanbuf[t - o] : 0;
    __syncthreads();
    scanbuf[t] += add;
    __syncthreads();
  }
  int pairExcl = scanbuf[t] - pair;
  int c0 = s + pairExcl;        // cursor/rowstart for node n0+2t
  int c1 = c0 + a0;             // for node n0+2t+1
  int n = n0 + 2 * t;
  if (n < N) {
    rowstart[n] = c0;
    dis[n] = rsqrtf((float)(a0 + 1));
  }
  if (n + 1 < N) {
    rowstart[n + 1] = c1;
    dis[n + 1] = rsqrtf((float)(a1 + 1));
  }
  if (b == SB - 1 && t == 0) rowstart[N] = E;
  // reuse hist as cursors
  hist[2 * t] = c0;
  hist[2 * t + 1] = c1;
  __syncthreads();
  for (int i = s + t; i < e1; i += 256) {
    uint32 pk = bbuf[i];
    int pos = atomicAdd(&hist[pk >> 17], 1);
    csrc[pos] = (int)(pk & 0x1FFFFu);
  }
}

// ---------------------------------------------------------------------------
// Fused prep: blocks [0,NLAYERS) do BN-affine precompute; the rest do graph
// boundaries from the sorted batch vector.
// ---------------------------------------------------------------------------
__global__ __launch_bounds__(256) void prep_k(const int* __restrict__ batch,
                                              int* __restrict__ gstart,
                                              const float* __restrict__ bconv,
                                              const float* __restrict__ gamma,
                                              const float* __restrict__ beta,
                                              const float* __restrict__ mean,
                                              const float* __restrict__ var,
                                              float* __restrict__ bns,
                                              float* __restrict__ bnt,
                                              int N, int G) {
  int t = threadIdx.x;
  if (blockIdx.x < NLAYERS) {
    if (t < FEAT) {
      int i = blockIdx.x * FEAT + t;
      float s = gamma[i] * rsqrtf(var[i] + EPS);
      bns[i] = s;
      bnt[i] = (bconv[i] - mean[i]) * s + beta[i];
    }
    return;
  }
  int n = (blockIdx.x - NLAYERS) * 256 + t;
  if (n >= N) return;
  int b = batch[n];
  int prev = (n == 0) ? -1 : batch[n - 1];
  for (int g = prev + 1; g <= b; ++g) gstart[g] = n;
  if (n == N - 1) {
    for (int g = b + 1; g <= G; ++g) gstart[g] = N;
  }
}

// ---------------------------------------------------------------------------
// xs = fp8_e4m3( dis[n] * (h @ blockdiag(W[l,0], W[l,1])) ), 1 byte/feature.
// h input: fp32 (layer 0) or packed-bf16 uint32 (layers 1,2), isBf16 flag.
// Tile: 64 nodes x 128 outputs per block (256 thr), 4x4 register tile/thread.
// ---------------------------------------------------------------------------
__global__ __launch_bounds__(256) void xw_k(const void* __restrict__ h, int isBf16,
                                            const float* __restrict__ W,  // + l*8192
                                            const float* __restrict__ dis,
                                            uint32* __restrict__ xs8, int N) {
  __shared__ float hT[64 * 68];  // [k][n], row stride 68 floats (272B, 16B-aligned)
  __shared__ float Ws[64 * 64];  // [k][j]
  const int t = threadIdx.x;
  const int a = t >> 4;   // node-quad 0..15
  const int b = t & 15;   // out-quad  0..15
  const int base = blockIdx.x * 64;

  for (int p = 0; p < 2; ++p) {
    // stage W[p] (4096 floats, contiguous)
    {
      const float4* src = (const float4*)(W + p * 4096);
      float4* dst = (float4*)Ws;
#pragma unroll
      for (int r = 0; r < 4; ++r) dst[r * 256 + t] = src[r * 256 + t];
    }
    // stage h tile transposed: hT[k][n] = h[base+n][p*64+k]
#pragma unroll
    for (int r = 0; r < 4; ++r) {
      int qid = r * 256 + t;   // 0..1023
      int n = qid >> 4;        // 0..63
      int q = qid & 15;        // k-quad
      float4 v = make_float4(0.f, 0.f, 0.f, 0.f);
      int node = base + n;
      if (node < N) {
        if (isBf16) {
          uint2 wv = *(const uint2*)((const uint32*)h + (size_t)node * 64 + p * 32 + q * 2);
          v.x = __uint_as_float(wv.x << 16);
          v.y = __uint_as_float(wv.x & 0xffff0000u);
          v.z = __uint_as_float(wv.y << 16);
          v.w = __uint_as_float(wv.y & 0xffff0000u);
        } else {
          v = *(const float4*)((const float*)h + (size_t)node * FEAT + p * 64 + q * 4);
        }
      }
      hT[(q * 4 + 0) * 68 + n] = v.x;
      hT[(q * 4 + 1) * 68 + n] = v.y;
      hT[(q * 4 + 2) * 68 + n] = v.z;
      hT[(q * 4 + 3) * 68 + n] = v.w;
    }
    __syncthreads();

    float acc[4][4];
#pragma unroll
    for (int i = 0; i < 4; ++i)
#pragma unroll
      for (int j = 0; j < 4; ++j) acc[i][j] = 0.f;

#pragma unroll 8
    for (int k = 0; k < 64; ++k) {
      float4 hv = *(const float4*)(hT + k * 68 + a * 4);
      float4 wv = *(const float4*)(Ws + k * 64 + b * 4);
      acc[0][0] += hv.x * wv.x; acc[0][1] += hv.x * wv.y; acc[0][2] += hv.x * wv.z; acc[0][3] += hv.x * wv.w;
      acc[1][0] += hv.y * wv.x; acc[1][1] += hv.y * wv.y; acc[1][2] += hv.y * wv.z; acc[1][3] += hv.y * wv.w;
      acc[2][0] += hv.z * wv.x; acc[2][1] += hv.z * wv.y; acc[2][2] += hv.z * wv.z; acc[2][3] += hv.z * wv.w;
      acc[3][0] += hv.w * wv.x; acc[3][1] += hv.w * wv.y; acc[3][2] += hv.w * wv.z; acc[3][3] += hv.w * wv.w;
    }

#pragma unroll
    for (int i = 0; i < 4; ++i) {
      int node = base + a * 4 + i;
      if (node < N) {
        float d = dis[node];
        int w = __builtin_amdgcn_cvt_pk_fp8_f32(acc[i][0] * d, acc[i][1] * d, 0, false);
        w = __builtin_amdgcn_cvt_pk_fp8_f32(acc[i][2] * d, acc[i][3] * d, w, true);
        xs8[(size_t)node * 32 + p * 16 + b] = (uint32)w;
      }
    }
    __syncthreads();
  }
}

// ---------------------------------------------------------------------------
// Gather + self-loop + BN/ReLU + pooled-sum fused. One wave per node, 4 waves
// per block (256 thr: best measured residency ~78% vs 56% for 512-thr).
// Lane holds feature pair as packed fp8x2 ushort (128B/row); 32-bit saddr
// addressing + packed f32x2 accumulate; unroll 16 independent fetches.
// ---------------------------------------------------------------------------
__global__ __launch_bounds__(256) void gather_k(const unsigned short* __restrict__ xs8,
                                                const float* __restrict__ dis,
                                                const int* __restrict__ rowstart,
                                                const int* __restrict__ csrc,
                                                const int* __restrict__ batch,
                                                const float* __restrict__ bns,  // + l*128
                                                const float* __restrict__ bnt,  // + l*128
                                                uint32* __restrict__ hout,
                                                float* __restrict__ sums,       // [G,384]
                                                int layer, int N) {
  const int w = threadIdx.x >> 6;       // wave 0..3
  const int lane = threadIdx.x & 63;
  const int wid = blockIdx.x * 4 + w;
  const bool valid = (wid < N);
  const int f = lane * 2;

  float rx = 0.f, ry = 0.f;
  int g = -1;

  if (valid) {
    int e0 = rowstart[wid];
    int e1 = rowstart[wid + 1];
    float di = dis[wid];

    int selfv = xs8[(uint32)wid * 64u + (uint32)lane];
    floatx2 acc = __builtin_amdgcn_cvt_pk_f32_fp8(selfv, false);

    for (int base = e0; base < e1; base += 64) {
      int cnt = min(64, e1 - base);
      int my = (lane < cnt) ? csrc[base + lane] : 0;
      int j = 0;
      for (; j + 15 < cnt; j += 16) {
        uint32 oo[16];
        int vv[16];
#pragma unroll
        for (int u = 0; u < 16; ++u) oo[u] = (uint32)__shfl(my, j + u) * 64u + (uint32)lane;
#pragma unroll
        for (int u = 0; u < 16; ++u) vv[u] = xs8[oo[u]];
#pragma unroll
        for (int u = 0; u < 16; ++u)
          acc += (floatx2)__builtin_amdgcn_cvt_pk_f32_fp8(vv[u], false);
      }
      for (; j + 3 < cnt; j += 4) {
        uint32 oo[4];
        int vv[4];
#pragma unroll
        for (int u = 0; u < 4; ++u) oo[u] = (uint32)__shfl(my, j + u) * 64u + (uint32)lane;
#pragma unroll
        for (int u = 0; u < 4; ++u) vv[u] = xs8[oo[u]];
#pragma unroll
        for (int u = 0; u < 4; ++u)
          acc += (floatx2)__builtin_amdgcn_cvt_pk_f32_fp8(vv[u], false);
      }
      for (; j < cnt; ++j) {
        uint32 off = (uint32)__shfl(my, j) * 64u + (uint32)lane;
        acc += (floatx2)__builtin_amdgcn_cvt_pk_f32_fp8((int)xs8[off], false);
      }
    }
    float ax = acc[0] * di;
    float ay = acc[1] * di;
    rx = fmaxf(ax * bns[f] + bnt[f], 0.f);
    ry = fmaxf(ay * bns[f + 1] + bnt[f + 1], 0.f);
    if (hout) hout[(uint32)wid * 64u + (uint32)lane] = pack_bf16(rx, ry);
    g = batch[wid];
  }

  // pooled-sum: reduce the block's 4 waves in LDS, 1 atomic per feature if
  // all 4 nodes belong to the same graph (true except at graph boundaries)
  __shared__ float ps[4][FEAT];
  __shared__ int gs[4];
  if (lane == 0) gs[w] = g;
  *(float2*)&ps[w][f] = make_float2(rx, ry);
  __syncthreads();
  bool same = (gs[0] >= 0) && (gs[1] == gs[0]) && (gs[2] == gs[0]) && (gs[3] == gs[0]);
  if (same) {
    int t = threadIdx.x;
    if (t < FEAT) {
      float s = ps[0][t] + ps[1][t] + ps[2][t] + ps[3][t];
      atomicAdd(&sums[(size_t)gs[0] * (NLAYERS * FEAT) + layer * FEAT + t], s);
    }
  } else if (valid) {
    float* sp = sums + (size_t)g * (NLAYERS * FEAT) + layer * FEAT + f;
    atomicAdd(sp, rx);
    atomicAdd(sp + 1, ry);
  }
}

// ---------------------------------------------------------------------------
// Head: pooled = sums/cnt; z1 = relu(pooled@W1+b1); z2 = z1@W2+b2; log_softmax.
// ---------------------------------------------------------------------------
__global__ __launch_bounds__(128) void head_k(const float* __restrict__ sums,
                                              const int* __restrict__ gstart,
                                              const float* __restrict__ W1,
                                              const float* __restrict__ b1,
                                              const float* __restrict__ W2,
                                              const float* __restrict__ b2,
                                              float* __restrict__ out) {
  __shared__ float pooled[NLAYERS * FEAT];
  __shared__ float z1[FEAT];
  __shared__ float z2[2];
  int g = blockIdx.x;
  int t = threadIdx.x;
  float cnt = (float)(gstart[g + 1] - gstart[g]);
  float inv = 1.f / fmaxf(cnt, 1.f);
  for (int k = t; k < NLAYERS * FEAT; k += 128) pooled[k] = sums[g * (NLAYERS * FEAT) + k] * inv;
  __syncthreads();
  float acc = b1[t];
  for (int k = 0; k < NLAYERS * FEAT; ++k) acc += pooled[k] * W1[k * FEAT + t];
  z1[t] = fmaxf(acc, 0.f);
  __syncthreads();
  if (t < 2) {
    float a = b2[t];
    for (int j = 0; j < FEAT; ++j) a += z1[j] * W2[j * 2 + t];
    z2[t] = a;
  }
  __syncthreads();
  if (t < 2) {
    float m = fmaxf(z2[0], z2[1]);
    float lse = m + logf(expf(z2[0] - m) + expf(z2[1] - m));
    out[g * 2 + t] = z2[t] - lse;
  }
}

// ---------------------------------------------------------------------------

extern "C" void kernel_launch(void* const* d_in, const int* in_sizes, int n_in,
                              void* d_out, int out_size, void* d_ws, size_t ws_size,
                              hipStream_t stream) {
  const float* x    = (const float*)d_in[0];
  const int*   ei   = (const int*)d_in[1];   // [2, E]
  const int*   batch= (const int*)d_in[2];   // [N]
  const float* Wc   = (const float*)d_in[3]; // [3,2,64,64]
  const float* bc   = (const float*)d_in[4]; // [3,2,64] == [3,128]
  const float* gam  = (const float*)d_in[5];
  const float* bet  = (const float*)d_in[6];
  const float* mu   = (const float*)d_in[7];
  const float* var  = (const float*)d_in[8];
  const float* W1   = (const float*)d_in[9];  // [384,128]
  const float* b1   = (const float*)d_in[10]; // [128]
  const float* W2   = (const float*)d_in[11]; // [128,2]
  const float* b2   = (const float*)d_in[12]; // [2]
  float* out = (float*)d_out;

  const int N = in_sizes[0] / FEAT;
  const int E = in_sizes[1] / 2;
  const int G = out_size / 2;
  const int SB = (N + (1 << SBSHIFT) - 1) >> SBSHIFT;  // super-buckets (<=256)
  const int NT = (E + TILE - 1) / TILE;                 // level-1 tiles

  const int* row = ei;
  const int* col = ei + E;

  // workspace carve (256B aligned)
  char* p = (char*)d_ws;
  auto alloc = [&](size_t bytes) -> void* {
    void* q = (void*)p;
    p += (bytes + 255) & ~(size_t)255;
    return q;
  };
  float*  dis      = (float*)alloc((size_t)N * 4);
  int*    rowstart = (int*)alloc((size_t)(N + 1) * 4);
  int*    csrc     = (int*)alloc((size_t)E * 4);
  int*    bsum     = (int*)alloc(1024 * 4);
  int*    gstart   = (int*)alloc(1024 * 4);
  int*    C        = (int*)alloc((size_t)256 * NT * 4);   // radix count matrix
  float*  bns      = (float*)alloc(NLAYERS * FEAT * 4);
  float*  bnt      = (float*)alloc(NLAYERS * FEAT * 4);
  float*  sums     = (float*)alloc((size_t)G * NLAYERS * FEAT * 4);
  uint32* bufA     = (uint32*)alloc((size_t)N * FEAT);    // xs fp8-packed (128B/row)
  uint32* bufB     = (uint32*)alloc((size_t)N * 64 * 4);  // h bf16-packed (256B/row)
  uint32* bbuf     = (uint32*)bufB;  // alias: partition buffer only used pre-layers

  const int nbN = (N + 255) / 256;
  const int Csz = SB * NT;
  const int nbC = (Csz + 255) / 256;

  hipMemsetAsync(sums, 0, (size_t)G * NLAYERS * FEAT * 4, stream);

  // CSR build: two-level radix partition, zero global atomics
  l1count_k<<<NT, 256, 0, stream>>>(col, C, E, NT, SB);
  scan1<<<nbC, 256, 0, stream>>>(C, bsum, Csz);
  scan2<<<1, 512, 0, stream>>>(bsum, nbC);
  gscan3<<<nbC, 256, 0, stream>>>(C, bsum, C, Csz);
  l1scatter_k<<<NT, 256, 0, stream>>>(row, col, C, bbuf, E, NT, SB);
  l2_k<<<SB, 256, 0, stream>>>(bbuf, C, rowstart, dis, csrc, N, E, NT, SB);

  // graph boundaries + fused BN params (single launch)
  prep_k<<<NLAYERS + nbN, 256, 0, stream>>>(batch, gstart, bc, gam, bet, mu, var,
                                            bns, bnt, N, G);

  // layers (pooling fused into gather_k; last layer skips hout store)
  const int xwBlocks = (N + 63) / 64;
  const int gaBlocks = (N + 3) / 4;
  const void* hin = (const void*)x;
  int isBf16 = 0;
  for (int l = 0; l < NLAYERS; ++l) {
    xw_k<<<xwBlocks, 256, 0, stream>>>(hin, isBf16, Wc + (size_t)l * 8192, dis, bufA, N);
    uint32* hptr = (l == NLAYERS - 1) ? nullptr : bufB;
    gather_k<<<gaBlocks, 256, 0, stream>>>((const unsigned short*)bufA, dis, rowstart,
                                           csrc, batch, bns + l * FEAT, bnt + l * FEAT,
                                           hptr, sums, l, N);
    hin = (const void*)bufB;
    isBf16 = 1;
  }

  head_k<<<G, 128, 0, stream>>>(sums, gstart, W1, b1, W2, b2, out);
}

// Round 13
// 609.614 us; speedup vs baseline: 1.0440x; 1.0440x over previous
//
#include <hip/hip_runtime.h>
#include <cstdint>
#include <cstddef>

// Problem constants (match reference)
#define FEAT 128          // IN_DIM == HID
#define NLAYERS 3
#define EPS 1e-5f
#define TILE 8192         // edges per radix-partition tile
#define SBSHIFT 9         // 512 nodes per super-bucket (N<=131072 -> SB<=256)

typedef unsigned int uint32;
typedef float floatx2 __attribute__((ext_vector_type(2)));

// pack two fp32 -> bf16 pair (RNE), low = even feature, high = odd feature
__device__ __forceinline__ uint32 pack_bf16(float a, float b) {
  uint32 ua = __float_as_uint(a);
  uint32 ub = __float_as_uint(b);
  ua += 0x7fffu + ((ua >> 16) & 1u);
  ub += 0x7fffu + ((ub >> 16) & 1u);
  return (ua >> 16) | (ub & 0xffff0000u);
}

// ---------------------------------------------------------------------------
// generic: per-256-block sums
__global__ void scan1(const int* __restrict__ in, int* __restrict__ bsum, int n) {
  __shared__ int s[256];
  int t = threadIdx.x;
  int i = blockIdx.x * 256 + t;
  s[t] = (i < n) ? in[i] : 0;
  __syncthreads();
  for (int o = 128; o > 0; o >>= 1) {
    if (t < o) s[t] += s[t + o];
    __syncthreads();
  }
  if (t == 0) bsum[blockIdx.x] = s[0];
}

// generic: single-block exclusive scan of block sums (nb <= 512)
__global__ void scan2(int* __restrict__ bsum, int nb) {
  __shared__ int s[512];
  int t = threadIdx.x;
  int v = (t < nb) ? bsum[t] : 0;
  s[t] = v;
  __syncthreads();
  for (int o = 1; o < 512; o <<= 1) {
    int add = (t >= o) ? s[t - o] : 0;
    __syncthreads();
    s[t] += add;
    __syncthreads();
  }
  if (t < nb) bsum[t] = s[t] - v;  // exclusive
}

// generic final scan: exclusive values written in-place (out may == in)
__global__ void gscan3(const int* __restrict__ in, const int* __restrict__ bsum,
                       int* __restrict__ out, int n) {
  __shared__ int s[256];
  int t = threadIdx.x;
  int i = blockIdx.x * 256 + t;
  int v = (i < n) ? in[i] : 0;
  s[t] = v;
  __syncthreads();
  for (int o = 1; o < 256; o <<= 1) {
    int add = (t >= o) ? s[t - o] : 0;
    __syncthreads();
    s[t] += add;
    __syncthreads();
  }
  if (i < n) out[i] = bsum[blockIdx.x] + s[t] - v;
}

// ---------------------------------------------------------------------------
// Radix partition level 1: count per (super-bucket, tile); bucket-major C.
// ---------------------------------------------------------------------------
__global__ __launch_bounds__(256) void l1count_k(const int* __restrict__ col,
                                                 int* __restrict__ C, int E, int NT,
                                                 int SB) {
  __shared__ int h[256];
  int t = threadIdx.x;
  h[t] = 0;
  __syncthreads();
  int base = blockIdx.x * TILE;
  int end = min(base + TILE, E);
  for (int i = base + t; i < end; i += 256) atomicAdd(&h[col[i] >> SBSHIFT], 1);
  __syncthreads();
  if (t < SB) C[t * NT + blockIdx.x] = h[t];
}

// level 1 scatter: contiguous runs per (tile,bucket); LDS atomics only.
// packed: (localcol 9b) << 17 | row (17b, N < 131072)
__global__ __launch_bounds__(256) void l1scatter_k(const int* __restrict__ row,
                                                   const int* __restrict__ col,
                                                   const int* __restrict__ Cex,
                                                   uint32* __restrict__ bbuf, int E, int NT,
                                                   int SB) {
  __shared__ int cur[256];
  int t = threadIdx.x;
  if (t < SB) cur[t] = Cex[t * NT + blockIdx.x];
  __syncthreads();
  int base = blockIdx.x * TILE;
  int end = min(base + TILE, E);
  for (int i = base + t; i < end; i += 256) {
    int c = col[i];
    int pos = atomicAdd(&cur[c >> SBSHIFT], 1);
    bbuf[pos] = ((uint32)(c & ((1 << SBSHIFT) - 1)) << 17) | (uint32)row[i];
  }
}

// ---------------------------------------------------------------------------
// Level 2 (fused): one block per super-bucket.
//   pass 1: LDS histogram of the bucket's 512 nodes (LDS atomics only)
//   LDS exclusive scan -> rowstart[n] = bucketStart + localExcl, dis[n]
//   pass 2: LDS cursors -> scatter csrc into the bucket's private window
// No global atomics anywhere; csrc writes confined to a contiguous window.
// ---------------------------------------------------------------------------
__global__ __launch_bounds__(256) void l2_k(const uint32* __restrict__ bbuf,
                                            const int* __restrict__ Cex,
                                            int* __restrict__ rowstart,
                                            float* __restrict__ dis,
                                            int* __restrict__ csrc,
                                            int N, int E, int NT, int SB) {
  __shared__ int hist[512];     // counts -> cursors
  __shared__ int scanbuf[256];  // pair-sum scan
  const int b = blockIdx.x;
  const int t = threadIdx.x;
  const int n0 = b << SBSHIFT;
  hist[t] = 0;
  hist[t + 256] = 0;
  __syncthreads();
  const int s = Cex[b * NT];
  const int e1 = (b == SB - 1) ? E : Cex[(b + 1) * NT];
  for (int i = s + t; i < e1; i += 256) {
    atomicAdd(&hist[bbuf[i] >> 17], 1);
  }
  __syncthreads();
  // exclusive scan of 512 counts: thread t owns elements 2t, 2t+1
  int a0 = hist[2 * t];
  int a1 = hist[2 * t + 1];
  int pair = a0 + a1;
  scanbuf[t] = pair;
  __syncthreads();
  for (int o = 1; o < 256; o <<= 1) {
    int add = (t >= o) ? scanbuf[t - o] : 0;
    __syncthreads();
    scanbuf[t] += add;
    __syncthreads();
  }
  int pairExcl = scanbuf[t] - pair;
  int c0 = s + pairExcl;        // cursor/rowstart for node n0+2t
  int c1 = c0 + a0;             // for node n0+2t+1
  int n = n0 + 2 * t;
  if (n < N) {
    rowstart[n] = c0;
    dis[n] = rsqrtf((float)(a0 + 1));
  }
  if (n + 1 < N) {
    rowstart[n + 1] = c1;
    dis[n + 1] = rsqrtf((float)(a1 + 1));
  }
  if (b == SB - 1 && t == 0) rowstart[N] = E;
  // reuse hist as cursors
  hist[2 * t] = c0;
  hist[2 * t + 1] = c1;
  __syncthreads();
  for (int i = s + t; i < e1; i += 256) {
    uint32 pk = bbuf[i];
    int pos = atomicAdd(&hist[pk >> 17], 1);
    csrc[pos] = (int)(pk & 0x1FFFFu);
  }
}

// ---------------------------------------------------------------------------
// Fused prep: blocks [0,NLAYERS) do BN-affine precompute; the rest do graph
// boundaries from the sorted batch vector.
// ---------------------------------------------------------------------------
__global__ __launch_bounds__(256) void prep_k(const int* __restrict__ batch,
                                              int* __restrict__ gstart,
                                              const float* __restrict__ bconv,
                                              const float* __restrict__ gamma,
                                              const float* __restrict__ beta,
                                              const float* __restrict__ mean,
                                              const float* __restrict__ var,
                                              float* __restrict__ bns,
                                              float* __restrict__ bnt,
                                              int N, int G) {
  int t = threadIdx.x;
  if (blockIdx.x < NLAYERS) {
    if (t < FEAT) {
      int i = blockIdx.x * FEAT + t;
      float s = gamma[i] * rsqrtf(var[i] + EPS);
      bns[i] = s;
      bnt[i] = (bconv[i] - mean[i]) * s + beta[i];
    }
    return;
  }
  int n = (blockIdx.x - NLAYERS) * 256 + t;
  if (n >= N) return;
  int b = batch[n];
  int prev = (n == 0) ? -1 : batch[n - 1];
  for (int g = prev + 1; g <= b; ++g) gstart[g] = n;
  if (n == N - 1) {
    for (int g = b + 1; g <= G; ++g) gstart[g] = N;
  }
}

// ---------------------------------------------------------------------------
// xs = fp8_e4m3( dis[n] * (h @ blockdiag(W[l,0], W[l,1])) ), 1 byte/feature.
// h input: fp32 (layer 0) or packed-bf16 uint32 (layers 1,2), isBf16 flag.
// Tile: 64 nodes x 128 outputs per block (256 thr), 4x4 register tile/thread.
// ---------------------------------------------------------------------------
__global__ __launch_bounds__(256) void xw_k(const void* __restrict__ h, int isBf16,
                                            const float* __restrict__ W,  // + l*8192
                                            const float* __restrict__ dis,
                                            uint32* __restrict__ xs8, int N) {
  __shared__ float hT[64 * 68];  // [k][n], row stride 68 floats (272B, 16B-aligned)
  __shared__ float Ws[64 * 64];  // [k][j]
  const int t = threadIdx.x;
  const int a = t >> 4;   // node-quad 0..15
  const int b = t & 15;   // out-quad  0..15
  const int base = blockIdx.x * 64;

  for (int p = 0; p < 2; ++p) {
    // stage W[p] (4096 floats, contiguous)
    {
      const float4* src = (const float4*)(W + p * 4096);
      float4* dst = (float4*)Ws;
#pragma unroll
      for (int r = 0; r < 4; ++r) dst[r * 256 + t] = src[r * 256 + t];
    }
    // stage h tile transposed: hT[k][n] = h[base+n][p*64+k]
#pragma unroll
    for (int r = 0; r < 4; ++r) {
      int qid = r * 256 + t;   // 0..1023
      int n = qid >> 4;        // 0..63
      int q = qid & 15;        // k-quad
      float4 v = make_float4(0.f, 0.f, 0.f, 0.f);
      int node = base + n;
      if (node < N) {
        if (isBf16) {
          uint2 wv = *(const uint2*)((const uint32*)h + (size_t)node * 64 + p * 32 + q * 2);
          v.x = __uint_as_float(wv.x << 16);
          v.y = __uint_as_float(wv.x & 0xffff0000u);
          v.z = __uint_as_float(wv.y << 16);
          v.w = __uint_as_float(wv.y & 0xffff0000u);
        } else {
          v = *(const float4*)((const float*)h + (size_t)node * FEAT + p * 64 + q * 4);
        }
      }
      hT[(q * 4 + 0) * 68 + n] = v.x;
      hT[(q * 4 + 1) * 68 + n] = v.y;
      hT[(q * 4 + 2) * 68 + n] = v.z;
      hT[(q * 4 + 3) * 68 + n] = v.w;
    }
    __syncthreads();

    float acc[4][4];
#pragma unroll
    for (int i = 0; i < 4; ++i)
#pragma unroll
      for (int j = 0; j < 4; ++j) acc[i][j] = 0.f;

#pragma unroll 8
    for (int k = 0; k < 64; ++k) {
      float4 hv = *(const float4*)(hT + k * 68 + a * 4);
      float4 wv = *(const float4*)(Ws + k * 64 + b * 4);
      acc[0][0] += hv.x * wv.x; acc[0][1] += hv.x * wv.y; acc[0][2] += hv.x * wv.z; acc[0][3] += hv.x * wv.w;
      acc[1][0] += hv.y * wv.x; acc[1][1] += hv.y * wv.y; acc[1][2] += hv.y * wv.z; acc[1][3] += hv.y * wv.w;
      acc[2][0] += hv.z * wv.x; acc[2][1] += hv.z * wv.y; acc[2][2] += hv.z * wv.z; acc[2][3] += hv.z * wv.w;
      acc[3][0] += hv.w * wv.x; acc[3][1] += hv.w * wv.y; acc[3][2] += hv.w * wv.z; acc[3][3] += hv.w * wv.w;
    }

#pragma unroll
    for (int i = 0; i < 4; ++i) {
      int node = base + a * 4 + i;
      if (node < N) {
        float d = dis[node];
        int w = __builtin_amdgcn_cvt_pk_fp8_f32(acc[i][0] * d, acc[i][1] * d, 0, false);
        w = __builtin_amdgcn_cvt_pk_fp8_f32(acc[i][2] * d, acc[i][3] * d, w, true);
        xs8[(size_t)node * 32 + p * 16 + b] = (uint32)w;
      }
    }
    __syncthreads();
  }
}

// ---------------------------------------------------------------------------
// Gather (wide-load formulation) + self-loop + BN/ReLU + pooled-sum fused.
// One wave per node, 8 waves/block. Each vector load covers FOUR rows
// (512B): lane = 16*sub + d loads uint2 (features 8d..8d+7) of edge j+sub.
// Each lane accumulates 8 features; a shfl_xor(16/32) butterfly merges the
// 4 subgroup partials. 4x fewer memory requests than the 2B/lane scheme.
// ---------------------------------------------------------------------------
__global__ __launch_bounds__(512) void gather_k(const uint2* __restrict__ xs2,
                                                const float* __restrict__ dis,
                                                const int* __restrict__ rowstart,
                                                const int* __restrict__ csrc,
                                                const int* __restrict__ batch,
                                                const float* __restrict__ bns,  // + l*128
                                                const float* __restrict__ bnt,  // + l*128
                                                uint32* __restrict__ hout,
                                                float* __restrict__ sums,       // [G,384]
                                                int layer, int N) {
  const int w = threadIdx.x >> 6;       // wave 0..7
  const int lane = threadIdx.x & 63;
  const int sub = lane >> 4;            // subgroup 0..3 (edge within quad)
  const int d = lane & 15;              // uint2 index within row (features 8d..8d+7)
  const int wid = blockIdx.x * 8 + w;
  const bool valid = (wid < N);

  float r[8];
#pragma unroll
  for (int k = 0; k < 8; ++k) r[k] = 0.f;
  int g = -1;

  if (valid) {
    int e0 = rowstart[wid];
    int e1 = rowstart[wid + 1];
    float di = dis[wid];

    floatx2 a01 = {0.f, 0.f}, a23 = {0.f, 0.f}, a45 = {0.f, 0.f}, a67 = {0.f, 0.f};
    // self-loop: only subgroup 0 loads; others contribute zero
    {
      uint2 v = make_uint2(0u, 0u);
      if (sub == 0) v = xs2[(uint32)wid * 16u + (uint32)d];
      a01 += (floatx2)__builtin_amdgcn_cvt_pk_f32_fp8((int)v.x, false);
      a23 += (floatx2)__builtin_amdgcn_cvt_pk_f32_fp8((int)v.x, true);
      a45 += (floatx2)__builtin_amdgcn_cvt_pk_f32_fp8((int)v.y, false);
      a67 += (floatx2)__builtin_amdgcn_cvt_pk_f32_fp8((int)v.y, true);
    }

    for (int base = e0; base < e1; base += 64) {
      int cnt = min(64, e1 - base);
      int my = (lane < cnt) ? csrc[base + lane] : 0;
      int j = 0;
      // full 16-edge groups: 4 wide loads in flight
      for (; j + 15 < cnt; j += 16) {
        uint2 vv[4];
#pragma unroll
        for (int u = 0; u < 4; ++u) {
          int s = __shfl(my, j + u * 4 + sub);
          vv[u] = xs2[(uint32)s * 16u + (uint32)d];
        }
#pragma unroll
        for (int u = 0; u < 4; ++u) {
          a01 += (floatx2)__builtin_amdgcn_cvt_pk_f32_fp8((int)vv[u].x, false);
          a23 += (floatx2)__builtin_amdgcn_cvt_pk_f32_fp8((int)vv[u].x, true);
          a45 += (floatx2)__builtin_amdgcn_cvt_pk_f32_fp8((int)vv[u].y, false);
          a67 += (floatx2)__builtin_amdgcn_cvt_pk_f32_fp8((int)vv[u].y, true);
        }
      }
      // tail: masked 4-edge groups
      for (; j < cnt; j += 4) {
        int ei = j + sub;
        uint2 v = make_uint2(0u, 0u);
        if (ei < cnt) {
          int s = __shfl(my, ei & 63);
          v = xs2[(uint32)s * 16u + (uint32)d];
        }
        a01 += (floatx2)__builtin_amdgcn_cvt_pk_f32_fp8((int)v.x, false);
        a23 += (floatx2)__builtin_amdgcn_cvt_pk_f32_fp8((int)v.x, true);
        a45 += (floatx2)__builtin_amdgcn_cvt_pk_f32_fp8((int)v.y, false);
        a67 += (floatx2)__builtin_amdgcn_cvt_pk_f32_fp8((int)v.y, true);
      }
    }

    // merge the 4 subgroup partials (lanes d, d+16, d+32, d+48)
    float acc[8] = {a01[0], a01[1], a23[0], a23[1], a45[0], a45[1], a67[0], a67[1]};
#pragma unroll
    for (int k = 0; k < 8; ++k) {
      acc[k] += __shfl_xor(acc[k], 16);
      acc[k] += __shfl_xor(acc[k], 32);
    }

    int fb = 8 * d;
#pragma unroll
    for (int k = 0; k < 8; ++k) {
      float a = acc[k] * di;
      r[k] = fmaxf(a * bns[fb + k] + bnt[fb + k], 0.f);
    }
    if (hout && sub == 0) {
      uint4 o;
      o.x = pack_bf16(r[0], r[1]);
      o.y = pack_bf16(r[2], r[3]);
      o.z = pack_bf16(r[4], r[5]);
      o.w = pack_bf16(r[6], r[7]);
      *(uint4*)(hout + (uint32)wid * 64u + (uint32)d * 4u) = o;
    }
    g = batch[wid];
  }

  // pooled-sum: reduce the block's 8 waves in LDS, 1 atomic per feature if
  // all 8 nodes belong to the same graph (true except at graph boundaries)
  __shared__ float ps[8][FEAT];
  __shared__ int gs[8];
  if (lane == 0) gs[w] = g;
  if (sub == 0) {
    *(float4*)&ps[w][8 * d] = make_float4(r[0], r[1], r[2], r[3]);
    *(float4*)&ps[w][8 * d + 4] = make_float4(r[4], r[5], r[6], r[7]);
  }
  __syncthreads();
  bool same = (gs[0] >= 0);
#pragma unroll
  for (int i = 1; i < 8; ++i) same = same && (gs[i] == gs[0]);
  if (same) {
    int t = threadIdx.x;
    if (t < FEAT) {
      float s = 0.f;
#pragma unroll
      for (int i = 0; i < 8; ++i) s += ps[i][t];
      atomicAdd(&sums[(size_t)gs[0] * (NLAYERS * FEAT) + layer * FEAT + t], s);
    }
  } else if (valid && sub == 0) {
    float* sp = sums + (size_t)g * (NLAYERS * FEAT) + layer * FEAT + 8 * d;
#pragma unroll
    for (int k = 0; k < 8; ++k) atomicAdd(sp + k, r[k]);
  }
}

// ---------------------------------------------------------------------------
// Head: pooled = sums/cnt; z1 = relu(pooled@W1+b1); z2 = z1@W2+b2; log_softmax.
// ---------------------------------------------------------------------------
__global__ __launch_bounds__(128) void head_k(const float* __restrict__ sums,
                                              const int* __restrict__ gstart,
                                              const float* __restrict__ W1,
                                              const float* __restrict__ b1,
                                              const float* __restrict__ W2,
                                              const float* __restrict__ b2,
                                              float* __restrict__ out) {
  __shared__ float pooled[NLAYERS * FEAT];
  __shared__ float z1[FEAT];
  __shared__ float z2[2];
  int g = blockIdx.x;
  int t = threadIdx.x;
  float cnt = (float)(gstart[g + 1] - gstart[g]);
  float inv = 1.f / fmaxf(cnt, 1.f);
  for (int k = t; k < NLAYERS * FEAT; k += 128) pooled[k] = sums[g * (NLAYERS * FEAT) + k] * inv;
  __syncthreads();
  float acc = b1[t];
  for (int k = 0; k < NLAYERS * FEAT; ++k) acc += pooled[k] * W1[k * FEAT + t];
  z1[t] = fmaxf(acc, 0.f);
  __syncthreads();
  if (t < 2) {
    float a = b2[t];
    for (int j = 0; j < FEAT; ++j) a += z1[j] * W2[j * 2 + t];
    z2[t] = a;
  }
  __syncthreads();
  if (t < 2) {
    float m = fmaxf(z2[0], z2[1]);
    float lse = m + logf(expf(z2[0] - m) + expf(z2[1] - m));
    out[g * 2 + t] = z2[t] - lse;
  }
}

// ---------------------------------------------------------------------------

extern "C" void kernel_launch(void* const* d_in, const int* in_sizes, int n_in,
                              void* d_out, int out_size, void* d_ws, size_t ws_size,
                              hipStream_t stream) {
  const float* x    = (const float*)d_in[0];
  const int*   ei   = (const int*)d_in[1];   // [2, E]
  const int*   batch= (const int*)d_in[2];   // [N]
  const float* Wc   = (const float*)d_in[3]; // [3,2,64,64]
  const float* bc   = (const float*)d_in[4]; // [3,2,64] == [3,128]
  const float* gam  = (const float*)d_in[5];
  const float* bet  = (const float*)d_in[6];
  const float* mu   = (const float*)d_in[7];
  const float* var  = (const float*)d_in[8];
  const float* W1   = (const float*)d_in[9];  // [384,128]
  const float* b1   = (const float*)d_in[10]; // [128]
  const float* W2   = (const float*)d_in[11]; // [128,2]
  const float* b2   = (const float*)d_in[12]; // [2]
  float* out = (float*)d_out;

  const int N = in_sizes[0] / FEAT;
  const int E = in_sizes[1] / 2;
  const int G = out_size / 2;
  const int SB = (N + (1 << SBSHIFT) - 1) >> SBSHIFT;  // super-buckets (<=256)
  const int NT = (E + TILE - 1) / TILE;                 // level-1 tiles

  const int* row = ei;
  const int* col = ei + E;

  // workspace carve (256B aligned)
  char* p = (char*)d_ws;
  auto alloc = [&](size_t bytes) -> void* {
    void* q = (void*)p;
    p += (bytes + 255) & ~(size_t)255;
    return q;
  };
  float*  dis      = (float*)alloc((size_t)N * 4);
  int*    rowstart = (int*)alloc((size_t)(N + 1) * 4);
  int*    csrc     = (int*)alloc((size_t)E * 4);
  int*    bsum     = (int*)alloc(1024 * 4);
  int*    gstart   = (int*)alloc(1024 * 4);
  int*    C        = (int*)alloc((size_t)256 * NT * 4);   // radix count matrix
  float*  bns      = (float*)alloc(NLAYERS * FEAT * 4);
  float*  bnt      = (float*)alloc(NLAYERS * FEAT * 4);
  float*  sums     = (float*)alloc((size_t)G * NLAYERS * FEAT * 4);
  uint32* bufA     = (uint32*)alloc((size_t)N * FEAT);    // xs fp8-packed (128B/row)
  uint32* bufB     = (uint32*)alloc((size_t)N * 64 * 4);  // h bf16-packed (256B/row)
  uint32* bbuf     = (uint32*)bufB;  // alias: partition buffer only used pre-layers

  const int nbN = (N + 255) / 256;
  const int Csz = SB * NT;
  const int nbC = (Csz + 255) / 256;

  hipMemsetAsync(sums, 0, (size_t)G * NLAYERS * FEAT * 4, stream);

  // CSR build: two-level radix partition, zero global atomics
  l1count_k<<<NT, 256, 0, stream>>>(col, C, E, NT, SB);
  scan1<<<nbC, 256, 0, stream>>>(C, bsum, Csz);
  scan2<<<1, 512, 0, stream>>>(bsum, nbC);
  gscan3<<<nbC, 256, 0, stream>>>(C, bsum, C, Csz);
  l1scatter_k<<<NT, 256, 0, stream>>>(row, col, C, bbuf, E, NT, SB);
  l2_k<<<SB, 256, 0, stream>>>(bbuf, C, rowstart, dis, csrc, N, E, NT, SB);

  // graph boundaries + fused BN params (single launch)
  prep_k<<<NLAYERS + nbN, 256, 0, stream>>>(batch, gstart, bc, gam, bet, mu, var,
                                            bns, bnt, N, G);

  // layers (pooling fused into gather_k; last layer skips hout store)
  const int xwBlocks = (N + 63) / 64;
  const int gaBlocks = (N + 7) / 8;
  const void* hin = (const void*)x;
  int isBf16 = 0;
  for (int l = 0; l < NLAYERS; ++l) {
    xw_k<<<xwBlocks, 256, 0, stream>>>(hin, isBf16, Wc + (size_t)l * 8192, dis, bufA, N);
    uint32* hptr = (l == NLAYERS - 1) ? nullptr : bufB;
    gather_k<<<gaBlocks, 512, 0, stream>>>((const uint2*)bufA, dis, rowstart,
                                           csrc, batch, bns + l * FEAT, bnt + l * FEAT,
                                           hptr, sums, l, N);
    hin = (const void*)bufB;
    isBf16 = 1;
  }

  head_k<<<G, 128, 0, stream>>>(sums, gstart, W1, b1, W2, b2, out);
}